// Round 6
// baseline (294.664 us; speedup 1.0000x reference)
//
#include <hip/hip_runtime.h>
#include <hip/hip_bf16.h>
#include <stdint.h>

typedef __bf16 bf16x8 __attribute__((ext_vector_type(8)));
typedef __bf16 bf16x4 __attribute__((ext_vector_type(4)));
typedef float f32x4 __attribute__((ext_vector_type(4)));

#define MFMA16(a, b, c) __builtin_amdgcn_mfma_f32_16x16x32_bf16((a), (b), (c), 0, 0, 0)
#define SB() __builtin_amdgcn_sched_barrier(0)

// fp32 -> bf16 RNE
__device__ __forceinline__ ushort f2bf(float f) {
  union { float f; uint32_t u; } a; a.f = f;
  uint32_t u = a.u;
  return (ushort)((u + 0x7fffu + ((u >> 16) & 1u)) >> 16);
}

// global -> LDS direct DMA, 16B per lane. LDS dest must be wave-uniform.
__device__ __forceinline__ void glds16(const void* g, void* l) {
  __builtin_amdgcn_global_load_lds(
      (const __attribute__((address_space(1))) uint32_t*)g,
      (__attribute__((address_space(3))) uint32_t*)l, 16, 0, 0);
}

// ---------------------------------------------------------------- converts
__global__ __launch_bounds__(256) void cvt_xy(const float* __restrict__ x,
                                              const float* __restrict__ y,
                                              ushort* __restrict__ xb,
                                              ushort* __restrict__ yb) {
  const int bid = blockIdx.x;
  const float* in;
  ushort* out;
  int i;
  if (bid < 2048) { in = x; out = xb; i = bid * 1024 + threadIdx.x * 4; }
  else            { in = y; out = yb; i = (bid - 2048) * 1024 + threadIdx.x * 4; }
  float4 v = *(const float4*)(in + i);
  ushort4 o;
  o.x = f2bf(v.x); o.y = f2bf(v.y); o.z = f2bf(v.z); o.w = f2bf(v.w);
  *(ushort4*)(out + i) = o;
}

__global__ __launch_bounds__(256) void cvt_w(
    const float* __restrict__ a, const float* __restrict__ b,
    const float* __restrict__ c, const float* __restrict__ d,
    ushort* __restrict__ oa, ushort* __restrict__ ob,
    ushort* __restrict__ oc, ushort* __restrict__ od) {
  const int bid = blockIdx.x;
  const int sel = bid >> 10;
  const int i = (bid & 1023) * 1024 + threadIdx.x * 4;
  const float* in = (sel == 0) ? a : (sel == 1) ? b : (sel == 2) ? c : d;
  ushort* out = (sel == 0) ? oa : (sel == 1) ? ob : (sel == 2) ? oc : od;
  float4 v = *(const float4*)(in + i);
  ushort4 o;
  o.x = f2bf(v.x); o.y = f2bf(v.y); o.z = f2bf(v.z); o.w = f2bf(v.w);
  *(ushort4*)(out + i) = o;
}

// ---------------------------------------------------------------- GEMM (B^T)
// out[m][n] = sum_k A[m][k] * Bw[n][k].  Double-buffered LDS, T3-min pipeline.
// EPI 0: bf16 out [M][1024], * scale
// EPI 1: bf16 out scattered to vT layout (B,H,D,L) = (2,16,64,4096)  (128x128 only)
// EPI 2: f32 out [M][1024] + bias
template <int EPI, int BM, int BN>
__global__ __launch_bounds__(256) void gemm_bt(
    const ushort* __restrict__ A, const ushort* __restrict__ Bw,
    void* __restrict__ Cout, int K, float scale, const float* __restrict__ bias) {
  constexpr int NN = 1024;
  constexpr int WM = BM / 2, WN = BN / 2;
  constexpr int AM = WM / 16, BNF = WN / 16;
  __shared__ ushort ldsA[2][BM * 32];
  __shared__ ushort ldsB[2][BN * 32];
  __shared__ ushort ldsT[(EPI == 1) ? (4 * 64 * 64) : 8];

  const int tid = threadIdx.x;
  const int w = tid >> 6, l = tid & 63;
  const int wm = w >> 1, wn = w & 1;
  const int m0 = blockIdx.x * BM, n0 = blockIdx.y * BN;

  f32x4 acc[AM][BNF] = {};

  const int srow = l >> 2;      // 16 rows per wave-issue (4 chunks of 16B per 64B row)
  const int schunk = l & 3;

  auto stage = [&](int buf, int kt) {
#pragma unroll
    for (int r = 0; r < BM / 64; ++r) {
      const int rb = r * 64 + w * 16;           // wave-uniform row base
      const int row = rb + srow;
      const int j = schunk ^ ((row >> 1) & 3);  // pre-swizzled global source chunk
      glds16(A + (size_t)(m0 + row) * K + kt + j * 8, (char*)&ldsA[buf][0] + rb * 64);
    }
#pragma unroll
    for (int r = 0; r < BN / 64; ++r) {
      const int rb = r * 64 + w * 16;
      const int row = rb + srow;
      const int j = schunk ^ ((row >> 1) & 3);
      glds16(Bw + (size_t)(n0 + row) * K + kt + j * 8, (char*)&ldsB[buf][0] + rb * 64);
    }
  };

  const int nt = K / 32;
  stage(0, 0);
  asm volatile("s_waitcnt vmcnt(0)" ::: "memory");
  SB(); __builtin_amdgcn_s_barrier(); SB();

  for (int t = 0; t < nt; ++t) {
    const int buf = t & 1;
    if (t + 1 < nt) stage(buf ^ 1, (t + 1) * 32);
    bf16x8 af[AM], bfr[BNF];
#pragma unroll
    for (int a = 0; a < AM; ++a) {
      const int rt = wm * WM + a * 16 + (l & 15);
      const int j = (l >> 4) ^ ((rt >> 1) & 3);
      af[a] = *(const bf16x8*)((const char*)&ldsA[buf][0] + rt * 64 + j * 16);
    }
#pragma unroll
    for (int bx = 0; bx < BNF; ++bx) {
      const int rt = wn * WN + bx * 16 + (l & 15);
      const int j = (l >> 4) ^ ((rt >> 1) & 3);
      bfr[bx] = *(const bf16x8*)((const char*)&ldsB[buf][0] + rt * 64 + j * 16);
    }
#pragma unroll
    for (int am = 0; am < AM; ++am)
#pragma unroll
      for (int bn = 0; bn < BNF; ++bn)
        acc[am][bn] = MFMA16(af[am], bfr[bn], acc[am][bn]);
    if (t + 1 < nt) {
      asm volatile("s_waitcnt vmcnt(0)" ::: "memory");
      SB(); __builtin_amdgcn_s_barrier(); SB();
    }
  }

  if constexpr (EPI == 0) {
#pragma unroll
    for (int am = 0; am < AM; ++am)
#pragma unroll
      for (int bn = 0; bn < BNF; ++bn)
#pragma unroll
        for (int i = 0; i < 4; ++i) {
          const int row = m0 + wm * WM + am * 16 + (l >> 4) * 4 + i;
          const int col = n0 + wn * WN + bn * 16 + (l & 15);
          ((ushort*)Cout)[(size_t)row * NN + col] = f2bf(acc[am][bn][i] * scale);
        }
  } else if constexpr (EPI == 2) {
#pragma unroll
    for (int am = 0; am < AM; ++am)
#pragma unroll
      for (int bn = 0; bn < BNF; ++bn)
#pragma unroll
        for (int i = 0; i < 4; ++i) {
          const int row = m0 + wm * WM + am * 16 + (l >> 4) * 4 + i;
          const int col = n0 + wn * WN + bn * 16 + (l & 15);
          ((float*)Cout)[(size_t)row * NN + col] = acc[am][bn][i] + bias[col];
        }
  } else {
    // EPI 1: transpose 64x64 wave tile in LDS, then coalesced stores along L.
    ushort* tp = ldsT + w * 4096;
#pragma unroll
    for (int am = 0; am < AM; ++am)
#pragma unroll
      for (int bn = 0; bn < BNF; ++bn)
#pragma unroll
        for (int i = 0; i < 4; ++i) {
          const int ml = am * 16 + (l >> 4) * 4 + i;
          const int cl = bn * 16 + (l & 15);
          tp[cl * 64 + ml] = f2bf(acc[am][bn][i]);
        }
    __syncthreads();
#pragma unroll
    for (int it = 0; it < 8; ++it) {
      const int cl = it * 8 + (l >> 3);
      const int mc = l & 7;
      bf16x8 vv = *(const bf16x8*)(tp + cl * 64 + mc * 8);
      const int gcol = n0 + wn * WN + cl;   // 0..1023 -> (h,d)
      const int gm = m0 + wm * WM + mc * 8; // 0..8191 -> (b,l_)
      const int b = gm >> 12;
      const int l_ = gm & 4095;
      const int h = gcol >> 6, d = gcol & 63;
      *(bf16x8*)((ushort*)Cout + (((size_t)b * 16 + h) * 64 + d) * 4096 + l_) = vv;
    }
  }
}

// ---------------------------------------------------------------- fused attention
// L-split waves: each of 4 waves owns a 32-l slice of every KV tile and covers
// ALL 64 q-rows (4 q-frags in registers).  kf/vf LDS fragments are reused over
// the 4 q-frags -> 8 ds_read_b128/wave-tile (was 32).  Each wave keeps its own
// online-softmax state (m,l,O) over its l-slice; one LDS merge per block at end.
// Row-sum computed in the MFMA pipe via a ones-column PV fragment (O-layout).
// lambda K-row ordering: MFMA la feeds A-row r with K[32w + 8(r>>2) + 4la + (r&3)]
// so pf[qa] = concat(sacc[0][qa], sacc[1][qa]) is the identity hardware-k A-frag.
// K swizzle sigma(rt) = 4*((rt>>3)&1) + (rt&3): 8 lanes/16B granule = conflict-free.
__global__ __launch_bounds__(256) void attn_fused(
    const ushort* __restrict__ qb, const ushort* __restrict__ kb,
    const ushort* __restrict__ vT, ushort* __restrict__ ao) {
  constexpr int H = 16, D = 64, L = 4096, N = 1024, KB = 128;
  __shared__ char ldsraw[2 * KB * 64 * 2 + 2 * 64 * KB * 2];  // 64KB: K dbuf + V dbuf
  __shared__ float ldsM[4][64];
  __shared__ float ldsL[4][64];
  ushort* ldsK0 = (ushort*)ldsraw;                    // [2][KB*64]
  ushort* ldsV0 = (ushort*)(ldsraw + 2 * KB * 64 * 2);  // [2][64*KB]
  float* ldsO = (float*)ldsraw;                       // merge alias [4][64][64]

  const int tid = threadIdx.x, w = tid >> 6, l = tid & 63;
  // XCD swizzle: 512 blocks = 8 XCDs x 64; each XCD owns 4 (b,h) values.
  const int wg = blockIdx.x;
  const int v = (wg & 7) * 64 + (wg >> 3);
  const int bh = v >> 4;
  const int n0 = (v & 15) * 64;
  const int b = bh >> 4, h = bh & 15;
  const int hq = l >> 4;   // lane quadrant
  const int m = l & 15;

  // Q fragments (B-operand), all 64 q-rows: qf[qa][ks], q = n0 + 16*qa + m
  bf16x8 qf[4][2];
#pragma unroll
  for (int qa = 0; qa < 4; ++qa) {
    const ushort* qp = qb + (((size_t)b * N + n0 + 16 * qa + m) * H + h) * D + hq * 8;
    qf[qa][0] = *(const bf16x8*)qp;
    qf[qa][1] = *(const bf16x8*)(qp + 32);
  }

  f32x4 oacc[4][4] = {};   // [qa][c]: O[q=16qa+4hq+i][d=16c+m]
  f32x4 lfr[4] = {};       // [qa]: row-sum in O-layout (ones-column PV)
  float m_run[4];          // [qa]: S-layout (q = 16qa+m)
#pragma unroll
  for (int qa = 0; qa < 4; ++qa) m_run[qa] = -1e30f;

  // ones B-frag for row-sum MFMA
  bf16x8 vones;
#pragma unroll
  for (int j = 0; j < 8; ++j) vones[j] = (__bf16)1.0f;

  auto stage = [&](int buf, int l0) {
#pragma unroll
    for (int r = 0; r < 4; ++r) {
      const int rb = (w * 4 + r) * 8;          // wave-uniform; 8 rows of 128B
      const int row = rb + (l >> 3);
      const int sk = 4 * ((row >> 3) & 1) + (row & 3);   // sigma(row)
      const int j = (l & 7) ^ sk;
      glds16(kb + (((size_t)b * L + l0 + row) * H + h) * D + j * 8,
             (char*)(ldsK0 + buf * KB * 64) + rb * 128);
    }
#pragma unroll
    for (int r = 0; r < 4; ++r) {
      const int rb = (w * 4 + r) * 4;          // wave-uniform; 4 rows of 256B
      const int row = rb + (l >> 4);
      const int j = (l & 15) ^ (row & 15);
      glds16(vT + ((size_t)(b * H + h) * D + row) * L + l0 + j * 8,
             (char*)(ldsV0 + buf * 64 * KB) + rb * 256);
    }
  };

  stage(0, 0);

  // lambda/sigma per-lane constants
  const int rtl = 32 * w + 8 * (m >> 2) + (m & 3);   // + 4*la
  const int sk = 4 * ((m >> 2) & 1) + (m & 3);

  for (int t = 0; t < L / KB; ++t) {
    const int buf = t & 1;
    if (t < L / KB - 1) {
      stage(buf ^ 1, (t + 1) * KB);
      asm volatile("s_waitcnt vmcnt(8)" ::: "memory");  // tile t's 8 loads done
    } else {
      asm volatile("s_waitcnt vmcnt(0)" ::: "memory");
    }
    SB(); __builtin_amdgcn_s_barrier(); SB();

    const char* kbase = (const char*)(ldsK0 + buf * KB * 64);
    const char* vbase = (const char*)(ldsV0 + buf * 64 * KB);

    // S^T = mfma(K, Q): sacc[la][qa]: lane holds S[q=16qa+m][l=32w+8hq+4la+i]
    f32x4 sacc[2][4] = {};
    __builtin_amdgcn_s_setprio(1);
#pragma unroll
    for (int la = 0; la < 2; ++la) {
      const int rt = rtl + 4 * la;
#pragma unroll
      for (int ks = 0; ks < 2; ++ks) {
        bf16x8 kf = *(const bf16x8*)(kbase + rt * 128 + (((ks * 4 + hq) ^ sk) << 4));
#pragma unroll
        for (int qa = 0; qa < 4; ++qa)
          sacc[la][qa] = MFMA16(kf, qf[qa][ks], sacc[la][qa]);
      }
    }
    __builtin_amdgcn_s_setprio(0);

    // in-lane online softmax (exp2 space; SCALE*log2e folded into q)
    float mt[4];
#pragma unroll
    for (int qa = 0; qa < 4; ++qa) {
      float a0 = fmaxf(fmaxf(sacc[0][qa][0], sacc[0][qa][1]),
                       fmaxf(sacc[0][qa][2], sacc[0][qa][3]));
      float a1 = fmaxf(fmaxf(sacc[1][qa][0], sacc[1][qa][1]),
                       fmaxf(sacc[1][qa][2], sacc[1][qa][3]));
      float mq = fmaxf(a0, a1);
      mq = fmaxf(mq, __shfl_xor(mq, 16, 64));
      mq = fmaxf(mq, __shfl_xor(mq, 32, 64));
      mt[qa] = mq;
    }
    // defer-max (T13): rescale only when some row's max grew by > 8
    bool ok = (mt[0] <= m_run[0] + 8.f) && (mt[1] <= m_run[1] + 8.f) &&
              (mt[2] <= m_run[2] + 8.f) && (mt[3] <= m_run[3] + 8.f);
    if (!__all(ok)) {
#pragma unroll
      for (int qa = 0; qa < 4; ++qa) {
        const float mn = fmaxf(m_run[qa], mt[qa]);
        const float corr = __builtin_amdgcn_exp2f(m_run[qa] - mn);
        m_run[qa] = mn;
        f32x4 co;
#pragma unroll
        for (int i = 0; i < 4; ++i) co[i] = __shfl(corr, hq * 4 + i, 64);
#pragma unroll
        for (int c = 0; c < 4; ++c) oacc[qa][c] *= co;
        lfr[qa] *= co;
      }
    }
    // P = exp2(S - m) and pack A-frags (identity hardware-k under lambda)
    bf16x8 pf[4];
#pragma unroll
    for (int qa = 0; qa < 4; ++qa)
#pragma unroll
      for (int i = 0; i < 4; ++i) {
        pf[qa][i]     = (__bf16)__builtin_amdgcn_exp2f(sacc[0][qa][i] - m_run[qa]);
        pf[qa][4 + i] = (__bf16)__builtin_amdgcn_exp2f(sacc[1][qa][i] - m_run[qa]);
      }

    // O += P V; row-sum via ones column (accumulates l in O-layout)
    __builtin_amdgcn_s_setprio(1);
#pragma unroll
    for (int c = 0; c < 4; ++c) {
      const int rt = c * 16 + m;            // V-row (d index)
      bf16x8 vf = *(const bf16x8*)(vbase + rt * 256 + ((((4 * w + hq)) ^ (rt & 15)) << 4));
#pragma unroll
      for (int qa = 0; qa < 4; ++qa)
        oacc[qa][c] = MFMA16(pf[qa], vf, oacc[qa][c]);
    }
#pragma unroll
    for (int qa = 0; qa < 4; ++qa) lfr[qa] = MFMA16(pf[qa], vones, lfr[qa]);
    __builtin_amdgcn_s_setprio(0);
    SB(); __builtin_amdgcn_s_barrier(); SB();  // all waves done reading buf
  }

  // ---- merge the 4 per-wave partial states ----
  // write partials (K/V buffers are dead after the final in-loop barrier)
#pragma unroll
  for (int qa = 0; qa < 4; ++qa)
#pragma unroll
    for (int c = 0; c < 4; ++c)
#pragma unroll
      for (int i = 0; i < 4; ++i)
        ldsO[w * 4096 + (16 * qa + 4 * hq + i) * 64 + 16 * c + m] = oacc[qa][c][i];
  if (hq == 0) {
#pragma unroll
    for (int qa = 0; qa < 4; ++qa) ldsM[w][16 * qa + m] = m_run[qa];
  }
  if (m == 0) {
#pragma unroll
    for (int qa = 0; qa < 4; ++qa)
#pragma unroll
      for (int i = 0; i < 4; ++i) ldsL[w][16 * qa + 4 * hq + i] = lfr[qa][i];
  }
  __syncthreads();

  // wave w merges q-rows [16w, 16w+16); lane: q = 16w+m, d = 16*hq + 0..15
  const int q = 16 * w + m;
  const float Mx = fmaxf(fmaxf(ldsM[0][q], ldsM[1][q]), fmaxf(ldsM[2][q], ldsM[3][q]));
  f32x4 av[4] = {};
  float Lt = 0.f;
#pragma unroll
  for (int wp = 0; wp < 4; ++wp) {
    const float sc = __builtin_amdgcn_exp2f(ldsM[wp][q] - Mx);
    Lt += ldsL[wp][q] * sc;
    const float* op = ldsO + wp * 4096 + q * 64 + hq * 16;
#pragma unroll
    for (int g = 0; g < 4; ++g) {
      f32x4 t4 = *(const f32x4*)(op + g * 4);
      av[g] += t4 * sc;
    }
  }
  const float inv = 1.0f / Lt;
  ushort* aop = ao + (((size_t)b * N + n0 + q) * H + h) * D + hq * 16;
#pragma unroll
  for (int g = 0; g < 4; ++g) {
    ushort4 o4;
    o4.x = f2bf(av[g][0] * inv); o4.y = f2bf(av[g][1] * inv);
    o4.z = f2bf(av[g][2] * inv); o4.w = f2bf(av[g][3] * inv);
    *(ushort4*)(aop + g * 4) = o4;
  }
}

// ---------------------------------------------------------------- launch
extern "C" void kernel_launch(void* const* d_in, const int* in_sizes, int n_in,
                              void* d_out, int out_size, void* d_ws, size_t ws_size,
                              hipStream_t stream) {
  const float* x  = (const float*)d_in[0];  // (2,1024,1024)
  const float* y  = (const float*)d_in[1];  // (2,4096,1024)
  const float* Wq = (const float*)d_in[2];
  const float* Wk = (const float*)d_in[3];
  const float* Wv = (const float*)d_in[4];
  const float* Wp = (const float*)d_in[5];
  const float* bp = (const float*)d_in[6];
  float* out = (float*)d_out;

  const size_t M1 = 1u << 20;
  ushort* wsb = (ushort*)d_ws;
  ushort* xb  = wsb;             // 2M elems
  ushort* yb  = wsb + 2 * M1;    // 8M
  ushort* wqb = wsb + 10 * M1;   // 1M
  ushort* wkb = wsb + 11 * M1;
  ushort* wvb = wsb + 12 * M1;
  ushort* wpb = wsb + 13 * M1;
  ushort* qbf = wsb + 14 * M1;   // 2M
  ushort* kbf = wsb + 16 * M1;   // 8M
  ushort* vtb = wsb + 24 * M1;   // 8M
  ushort* aob = wsb + 32 * M1;   // 2M  (total 34M elems = 68 MB)

  cvt_xy<<<10240, 256, 0, stream>>>(x, y, xb, yb);
  cvt_w<<<4096, 256, 0, stream>>>(Wq, Wk, Wv, Wp, wqb, wkb, wvb, wpb);

  const float qscale = 0.125f * 1.4426950408889634f;  // SCALE * log2(e)
  gemm_bt<0, 64, 64><<<dim3(32, 16), 256, 0, stream>>>(xb, wqb, qbf, 1024, qscale, nullptr);
  gemm_bt<0, 128, 128><<<dim3(64, 8), 256, 0, stream>>>(yb, wkb, kbf, 1024, 1.0f, nullptr);
  gemm_bt<1, 128, 128><<<dim3(64, 8), 256, 0, stream>>>(yb, wvb, vtb, 1024, 1.0f, nullptr);

  attn_fused<<<512, 256, 0, stream>>>(qbf, kbf, vtb, aob);

  gemm_bt<2, 64, 64><<<dim3(32, 16), 256, 0, stream>>>(aob, wpb, out, 1024, 1.0f, bp);
}

// Round 7
// 247.106 us; speedup vs baseline: 1.1925x; 1.1925x over previous
//
#include <hip/hip_runtime.h>
#include <hip/hip_bf16.h>
#include <stdint.h>

typedef __bf16 bf16x8 __attribute__((ext_vector_type(8)));
typedef __bf16 bf16x4 __attribute__((ext_vector_type(4)));
typedef float f32x4 __attribute__((ext_vector_type(4)));

#define MFMA16(a, b, c) __builtin_amdgcn_mfma_f32_16x16x32_bf16((a), (b), (c), 0, 0, 0)
#define SB() __builtin_amdgcn_sched_barrier(0)

// fp32 -> bf16 RNE
__device__ __forceinline__ ushort f2bf(float f) {
  union { float f; uint32_t u; } a; a.f = f;
  uint32_t u = a.u;
  return (ushort)((u + 0x7fffu + ((u >> 16) & 1u)) >> 16);
}

// global -> LDS direct DMA, 16B per lane. LDS dest must be wave-uniform.
__device__ __forceinline__ void glds16(const void* g, void* l) {
  __builtin_amdgcn_global_load_lds(
      (const __attribute__((address_space(1))) uint32_t*)g,
      (__attribute__((address_space(3))) uint32_t*)l, 16, 0, 0);
}

// ---------------------------------------------------------------- converts
__global__ __launch_bounds__(256) void cvt_xy(const float* __restrict__ x,
                                              const float* __restrict__ y,
                                              ushort* __restrict__ xb,
                                              ushort* __restrict__ yb) {
  const int bid = blockIdx.x;
  const float* in;
  ushort* out;
  int i;
  if (bid < 2048) { in = x; out = xb; i = bid * 1024 + threadIdx.x * 4; }
  else            { in = y; out = yb; i = (bid - 2048) * 1024 + threadIdx.x * 4; }
  float4 v = *(const float4*)(in + i);
  ushort4 o;
  o.x = f2bf(v.x); o.y = f2bf(v.y); o.z = f2bf(v.z); o.w = f2bf(v.w);
  *(ushort4*)(out + i) = o;
}

__global__ __launch_bounds__(256) void cvt_w(
    const float* __restrict__ a, const float* __restrict__ b,
    const float* __restrict__ c, const float* __restrict__ d,
    ushort* __restrict__ oa, ushort* __restrict__ ob,
    ushort* __restrict__ oc, ushort* __restrict__ od) {
  const int bid = blockIdx.x;
  const int sel = bid >> 10;
  const int i = (bid & 1023) * 1024 + threadIdx.x * 4;
  const float* in = (sel == 0) ? a : (sel == 1) ? b : (sel == 2) ? c : d;
  ushort* out = (sel == 0) ? oa : (sel == 1) ? ob : (sel == 2) ? oc : od;
  float4 v = *(const float4*)(in + i);
  ushort4 o;
  o.x = f2bf(v.x); o.y = f2bf(v.y); o.z = f2bf(v.z); o.w = f2bf(v.w);
  *(ushort4*)(out + i) = o;
}

// ---------------------------------------------------------------- GEMM (B^T)
// out[m][n] = sum_k A[m][k] * Bw[n][k].  Double-buffered LDS, T3-min pipeline.
// EPI 0: bf16 out [M][1024], * scale
// EPI 1: bf16 out scattered to vT layout (B,H,D,L) = (2,16,64,4096)  (128x128 only)
// EPI 2: f32 out [M][1024] + bias
template <int EPI, int BM, int BN>
__global__ __launch_bounds__(256) void gemm_bt(
    const ushort* __restrict__ A, const ushort* __restrict__ Bw,
    void* __restrict__ Cout, int K, float scale, const float* __restrict__ bias) {
  constexpr int NN = 1024;
  constexpr int WM = BM / 2, WN = BN / 2;
  constexpr int AM = WM / 16, BNF = WN / 16;
  __shared__ ushort ldsA[2][BM * 32];
  __shared__ ushort ldsB[2][BN * 32];
  __shared__ ushort ldsT[(EPI == 1) ? (4 * 64 * 64) : 8];

  const int tid = threadIdx.x;
  const int w = tid >> 6, l = tid & 63;
  const int wm = w >> 1, wn = w & 1;
  const int m0 = blockIdx.x * BM, n0 = blockIdx.y * BN;

  f32x4 acc[AM][BNF] = {};

  const int srow = l >> 2;      // 16 rows per wave-issue (4 chunks of 16B per 64B row)
  const int schunk = l & 3;

  auto stage = [&](int buf, int kt) {
#pragma unroll
    for (int r = 0; r < BM / 64; ++r) {
      const int rb = r * 64 + w * 16;           // wave-uniform row base
      const int row = rb + srow;
      const int j = schunk ^ ((row >> 1) & 3);  // pre-swizzled global source chunk
      glds16(A + (size_t)(m0 + row) * K + kt + j * 8, (char*)&ldsA[buf][0] + rb * 64);
    }
#pragma unroll
    for (int r = 0; r < BN / 64; ++r) {
      const int rb = r * 64 + w * 16;
      const int row = rb + srow;
      const int j = schunk ^ ((row >> 1) & 3);
      glds16(Bw + (size_t)(n0 + row) * K + kt + j * 8, (char*)&ldsB[buf][0] + rb * 64);
    }
  };

  const int nt = K / 32;
  stage(0, 0);
  asm volatile("s_waitcnt vmcnt(0)" ::: "memory");
  SB(); __builtin_amdgcn_s_barrier(); SB();

  for (int t = 0; t < nt; ++t) {
    const int buf = t & 1;
    if (t + 1 < nt) stage(buf ^ 1, (t + 1) * 32);
    bf16x8 af[AM], bfr[BNF];
#pragma unroll
    for (int a = 0; a < AM; ++a) {
      const int rt = wm * WM + a * 16 + (l & 15);
      const int j = (l >> 4) ^ ((rt >> 1) & 3);
      af[a] = *(const bf16x8*)((const char*)&ldsA[buf][0] + rt * 64 + j * 16);
    }
#pragma unroll
    for (int bx = 0; bx < BNF; ++bx) {
      const int rt = wn * WN + bx * 16 + (l & 15);
      const int j = (l >> 4) ^ ((rt >> 1) & 3);
      bfr[bx] = *(const bf16x8*)((const char*)&ldsB[buf][0] + rt * 64 + j * 16);
    }
#pragma unroll
    for (int am = 0; am < AM; ++am)
#pragma unroll
      for (int bn = 0; bn < BNF; ++bn)
        acc[am][bn] = MFMA16(af[am], bfr[bn], acc[am][bn]);
    if (t + 1 < nt) {
      asm volatile("s_waitcnt vmcnt(0)" ::: "memory");
      SB(); __builtin_amdgcn_s_barrier(); SB();
    }
  }

  if constexpr (EPI == 0) {
#pragma unroll
    for (int am = 0; am < AM; ++am)
#pragma unroll
      for (int bn = 0; bn < BNF; ++bn)
#pragma unroll
        for (int i = 0; i < 4; ++i) {
          const int row = m0 + wm * WM + am * 16 + (l >> 4) * 4 + i;
          const int col = n0 + wn * WN + bn * 16 + (l & 15);
          ((ushort*)Cout)[(size_t)row * NN + col] = f2bf(acc[am][bn][i] * scale);
        }
  } else if constexpr (EPI == 2) {
#pragma unroll
    for (int am = 0; am < AM; ++am)
#pragma unroll
      for (int bn = 0; bn < BNF; ++bn)
#pragma unroll
        for (int i = 0; i < 4; ++i) {
          const int row = m0 + wm * WM + am * 16 + (l >> 4) * 4 + i;
          const int col = n0 + wn * WN + bn * 16 + (l & 15);
          ((float*)Cout)[(size_t)row * NN + col] = acc[am][bn][i] + bias[col];
        }
  } else {
    // EPI 1: transpose 64x64 wave tile in LDS, then coalesced stores along L.
    ushort* tp = ldsT + w * 4096;
#pragma unroll
    for (int am = 0; am < AM; ++am)
#pragma unroll
      for (int bn = 0; bn < BNF; ++bn)
#pragma unroll
        for (int i = 0; i < 4; ++i) {
          const int ml = am * 16 + (l >> 4) * 4 + i;
          const int cl = bn * 16 + (l & 15);
          tp[cl * 64 + ml] = f2bf(acc[am][bn][i]);
        }
    __syncthreads();
#pragma unroll
    for (int it = 0; it < 8; ++it) {
      const int cl = it * 8 + (l >> 3);
      const int mc = l & 7;
      bf16x8 vv = *(const bf16x8*)(tp + cl * 64 + mc * 8);
      const int gcol = n0 + wn * WN + cl;   // 0..1023 -> (h,d)
      const int gm = m0 + wm * WM + mc * 8; // 0..8191 -> (b,l_)
      const int b = gm >> 12;
      const int l_ = gm & 4095;
      const int h = gcol >> 6, d = gcol & 63;
      *(bf16x8*)((ushort*)Cout + (((size_t)b * 16 + h) * 64 + d) * 4096 + l_) = vv;
    }
  }
}

// ---------------------------------------------------------------- fused attention
// Hybrid 2x2 wave split: wave w = (wq = w>>1, wl = w&1).  Each wave covers
// 32 q-rows (2 q-frags) x 64 l (half the KV tile).  kf/vf fragments reused
// across the 2 q-frags -> 16 ds_read_b128/wave-tile (R5 had 32) while register
// state stays ~140 (R6's 4-q split hit ~270 incl. AGPRs -> 1 wave/SIMD).
// lambda K-row ordering per 32-l group g: A-row r <- K[64wl+32g+8(r>>2)+4la+(r&3)]
// so pf = concat(sacc[g][0],sacc[g][1]) is the identity hardware-k PV A-frag.
// sigma(rt) = 4*((rt>>3)&1)+(rt&3) K-swizzle (verified R5/R6).  Per-wave online
// softmax over its l-half; 2-way merge in LDS at the end (ldsO stride 68 floats
// to kill the 4-way merge-write bank conflict seen in R6).
__global__ __launch_bounds__(256) void attn_fused(
    const ushort* __restrict__ qb, const ushort* __restrict__ kb,
    const ushort* __restrict__ vT, ushort* __restrict__ ao) {
  constexpr int H = 16, D = 64, L = 4096, N = 1024, KB = 128;
  __shared__ char ldsraw[2 * KB * 64 * 2 + 2 * 64 * KB * 2];  // 64KB: K dbuf + V dbuf
  __shared__ float ldsM[4][32];
  __shared__ float ldsL[4][32];
  ushort* ldsK0 = (ushort*)ldsraw;                      // [2][KB*64]
  ushort* ldsV0 = (ushort*)(ldsraw + 2 * KB * 64 * 2);  // [2][64*KB]
  float* ldsO = (float*)ldsraw;                         // merge alias [4][32][68]

  const int tid = threadIdx.x, w = tid >> 6, l = tid & 63;
  const int wq = w >> 1, wl = w & 1;
  // XCD swizzle: 512 blocks = 8 XCDs x 64; each XCD owns 4 (b,h) values.
  const int wg = blockIdx.x;
  const int v = (wg & 7) * 64 + (wg >> 3);
  const int bh = v >> 4;
  const int n0 = (v & 15) * 64;
  const int b = bh >> 4, h = bh & 15;
  const int hq = l >> 4;   // lane quadrant
  const int m = l & 15;

  // Q fragments (B-operand): qf[qa][ks], q = n0 + 32*wq + 16*qa + m
  bf16x8 qf[2][2];
#pragma unroll
  for (int qa = 0; qa < 2; ++qa) {
    const ushort* qp = qb + (((size_t)b * N + n0 + 32 * wq + 16 * qa + m) * H + h) * D + hq * 8;
    qf[qa][0] = *(const bf16x8*)qp;
    qf[qa][1] = *(const bf16x8*)(qp + 32);
  }

  f32x4 oacc[2][4] = {};   // [qa][c]: O[q=16qa+4hq+i][d=16c+m]  (within wave's 32 q)
  f32x4 lfr[2] = {};       // [qa]: row-sum in O-layout (ones-column PV)
  float m_run[2] = {-1e30f, -1e30f};

  bf16x8 vones;
#pragma unroll
  for (int j = 0; j < 8; ++j) vones[j] = (__bf16)1.0f;

  auto stage = [&](int buf, int l0) {
#pragma unroll
    for (int r = 0; r < 4; ++r) {
      const int rb = (w * 4 + r) * 8;          // wave-uniform; 8 rows of 128B
      const int row = rb + (l >> 3);
      const int sk = 4 * ((row >> 3) & 1) + (row & 3);   // sigma(row)
      const int j = (l & 7) ^ sk;
      glds16(kb + (((size_t)b * L + l0 + row) * H + h) * D + j * 8,
             (char*)(ldsK0 + buf * KB * 64) + rb * 128);
    }
#pragma unroll
    for (int r = 0; r < 4; ++r) {
      const int rb = (w * 4 + r) * 4;          // wave-uniform; 4 rows of 256B
      const int row = rb + (l >> 4);
      const int j = (l & 15) ^ (row & 15);
      glds16(vT + ((size_t)(b * H + h) * D + row) * L + l0 + j * 8,
             (char*)(ldsV0 + buf * 64 * KB) + rb * 256);
    }
  };

  stage(0, 0);

  // lambda/sigma per-lane constants
  const int sk = 4 * ((m >> 2) & 1) + (m & 3);
  const int rbase = 64 * wl + 8 * (m >> 2) + (m & 3);   // + 32g + 4la

  for (int t = 0; t < L / KB; ++t) {
    const int buf = t & 1;
    if (t < L / KB - 1) {
      stage(buf ^ 1, (t + 1) * KB);
      asm volatile("s_waitcnt vmcnt(8)" ::: "memory");  // tile t's 8 loads done
    } else {
      asm volatile("s_waitcnt vmcnt(0)" ::: "memory");
    }
    SB(); __builtin_amdgcn_s_barrier(); SB();

    const char* kbase = (const char*)(ldsK0 + buf * KB * 64);
    const char* vbase = (const char*)(ldsV0 + buf * 64 * KB);

    // S^T = mfma(K, Q): sacc[g][la][qa]: S[q=32wq+16qa+m][l=64wl+32g+8hq+4la+i]
    f32x4 sacc[2][2][2] = {};
    __builtin_amdgcn_s_setprio(1);
#pragma unroll
    for (int g = 0; g < 2; ++g)
#pragma unroll
      for (int la = 0; la < 2; ++la) {
        const int rt = rbase + 32 * g + 4 * la;
#pragma unroll
        for (int ks = 0; ks < 2; ++ks) {
          bf16x8 kf = *(const bf16x8*)(kbase + rt * 128 + (((ks * 4 + hq) ^ sk) << 4));
#pragma unroll
          for (int qa = 0; qa < 2; ++qa)
            sacc[g][la][qa] = MFMA16(kf, qf[qa][ks], sacc[g][la][qa]);
        }
      }
    __builtin_amdgcn_s_setprio(0);

    // in-lane online softmax (exp2 space; SCALE*log2e folded into q)
    float mt[2];
#pragma unroll
    for (int qa = 0; qa < 2; ++qa) {
      float mq = sacc[0][0][qa][0];
#pragma unroll
      for (int g = 0; g < 2; ++g)
#pragma unroll
        for (int la = 0; la < 2; ++la)
#pragma unroll
          for (int i = 0; i < 4; ++i) mq = fmaxf(mq, sacc[g][la][qa][i]);
      mq = fmaxf(mq, __shfl_xor(mq, 16, 64));
      mq = fmaxf(mq, __shfl_xor(mq, 32, 64));
      mt[qa] = mq;
    }
    // defer-max (T13): rescale only when some row's max grew by > 8
    const bool ok = (mt[0] <= m_run[0] + 8.f) && (mt[1] <= m_run[1] + 8.f);
    if (!__all(ok)) {
#pragma unroll
      for (int qa = 0; qa < 2; ++qa) {
        const float mn = fmaxf(m_run[qa], mt[qa]);
        const float corr = __builtin_amdgcn_exp2f(m_run[qa] - mn);
        m_run[qa] = mn;
        f32x4 co;
#pragma unroll
        for (int i = 0; i < 4; ++i) co[i] = __shfl(corr, hq * 4 + i, 64);
#pragma unroll
        for (int c = 0; c < 4; ++c) oacc[qa][c] *= co;
        lfr[qa] *= co;
      }
    }
    // P = exp2(S - m), packed as PV A-frags (identity hardware-k under lambda)
    bf16x8 pf[2][2];   // [g][qa]
#pragma unroll
    for (int g = 0; g < 2; ++g)
#pragma unroll
      for (int qa = 0; qa < 2; ++qa)
#pragma unroll
        for (int i = 0; i < 4; ++i) {
          pf[g][qa][i]     = (__bf16)__builtin_amdgcn_exp2f(sacc[g][0][qa][i] - m_run[qa]);
          pf[g][qa][4 + i] = (__bf16)__builtin_amdgcn_exp2f(sacc[g][1][qa][i] - m_run[qa]);
        }

    // O += P V; row-sum via ones column (O-layout l)
    __builtin_amdgcn_s_setprio(1);
#pragma unroll
    for (int g = 0; g < 2; ++g) {
#pragma unroll
      for (int c = 0; c < 4; ++c) {
        const int rt = c * 16 + m;            // V-row (d index)
        const int j = (8 * wl + 4 * g + hq) ^ (rt & 15);
        bf16x8 vf = *(const bf16x8*)(vbase + rt * 256 + (j << 4));
#pragma unroll
        for (int qa = 0; qa < 2; ++qa)
          oacc[qa][c] = MFMA16(pf[g][qa], vf, oacc[qa][c]);
      }
#pragma unroll
      for (int qa = 0; qa < 2; ++qa) lfr[qa] = MFMA16(pf[g][qa], vones, lfr[qa]);
    }
    __builtin_amdgcn_s_setprio(0);
    SB(); __builtin_amdgcn_s_barrier(); SB();  // all waves done reading buf
  }

  // ---- 2-way merge of wl partials (K/V buffers dead after final barrier) ----
  // partial store: ldsO[w][q_local 0..31][68]  (stride 68 floats: conflict-free)
#pragma unroll
  for (int qa = 0; qa < 2; ++qa)
#pragma unroll
    for (int c = 0; c < 4; ++c)
#pragma unroll
      for (int i = 0; i < 4; ++i)
        ldsO[w * 2176 + (16 * qa + 4 * hq + i) * 68 + 16 * c + m] = oacc[qa][c][i];
  if (hq == 0) {
#pragma unroll
    for (int qa = 0; qa < 2; ++qa) ldsM[w][16 * qa + m] = m_run[qa];
  }
  if (m == 0) {
#pragma unroll
    for (int qa = 0; qa < 2; ++qa)
#pragma unroll
      for (int i = 0; i < 4; ++i) ldsL[w][16 * qa + 4 * hq + i] = lfr[qa][i];
  }
  __syncthreads();

  // wave w merges q-rows [16w, 16w+16): lane q = 16w + m, d = 16*hq + 0..15
  const int q_local = 16 * (w & 1) + m;           // within source waves' 32 rows
  const int p0 = (w >> 1) * 2;                    // source waves (wl=0,1)
  const float Mx = fmaxf(ldsM[p0][q_local], ldsM[p0 + 1][q_local]);
  f32x4 av[4] = {};
  float Lt = 0.f;
#pragma unroll
  for (int p = 0; p < 2; ++p) {
    const int ws = p0 + p;
    const float sc = __builtin_amdgcn_exp2f(ldsM[ws][q_local] - Mx);
    Lt += ldsL[ws][q_local] * sc;
    const float* op = ldsO + ws * 2176 + q_local * 68 + hq * 16;
#pragma unroll
    for (int g = 0; g < 4; ++g) {
      f32x4 t4 = *(const f32x4*)(op + g * 4);
      av[g] += t4 * sc;
    }
  }
  const float inv = 1.0f / Lt;
  ushort* aop = ao + (((size_t)b * N + n0 + 16 * w + m) * H + h) * D + hq * 16;
#pragma unroll
  for (int g = 0; g < 4; ++g) {
    ushort4 o4;
    o4.x = f2bf(av[g][0] * inv); o4.y = f2bf(av[g][1] * inv);
    o4.z = f2bf(av[g][2] * inv); o4.w = f2bf(av[g][3] * inv);
    *(ushort4*)(aop + g * 4) = o4;
  }
}

// ---------------------------------------------------------------- launch
extern "C" void kernel_launch(void* const* d_in, const int* in_sizes, int n_in,
                              void* d_out, int out_size, void* d_ws, size_t ws_size,
                              hipStream_t stream) {
  const float* x  = (const float*)d_in[0];  // (2,1024,1024)
  const float* y  = (const float*)d_in[1];  // (2,4096,1024)
  const float* Wq = (const float*)d_in[2];
  const float* Wk = (const float*)d_in[3];
  const float* Wv = (const float*)d_in[4];
  const float* Wp = (const float*)d_in[5];
  const float* bp = (const float*)d_in[6];
  float* out = (float*)d_out;

  const size_t M1 = 1u << 20;
  ushort* wsb = (ushort*)d_ws;
  ushort* xb  = wsb;             // 2M elems
  ushort* yb  = wsb + 2 * M1;    // 8M
  ushort* wqb = wsb + 10 * M1;   // 1M
  ushort* wkb = wsb + 11 * M1;
  ushort* wvb = wsb + 12 * M1;
  ushort* wpb = wsb + 13 * M1;
  ushort* qbf = wsb + 14 * M1;   // 2M
  ushort* kbf = wsb + 16 * M1;   // 8M
  ushort* vtb = wsb + 24 * M1;   // 8M
  ushort* aob = wsb + 32 * M1;   // 2M  (total 34M elems = 68 MB)

  cvt_xy<<<10240, 256, 0, stream>>>(x, y, xb, yb);
  cvt_w<<<4096, 256, 0, stream>>>(Wq, Wk, Wv, Wp, wqb, wkb, wvb, wpb);

  const float qscale = 0.125f * 1.4426950408889634f;  // SCALE * log2(e)
  gemm_bt<0, 64, 64><<<dim3(32, 16), 256, 0, stream>>>(xb, wqb, qbf, 1024, qscale, nullptr);
  gemm_bt<0, 128, 128><<<dim3(64, 8), 256, 0, stream>>>(yb, wkb, kbf, 1024, 1.0f, nullptr);
  gemm_bt<1, 128, 128><<<dim3(64, 8), 256, 0, stream>>>(yb, wvb, vtb, 1024, 1.0f, nullptr);

  attn_fused<<<512, 256, 0, stream>>>(qbf, kbf, vtb, aob);

  gemm_bt<2, 64, 64><<<dim3(32, 16), 256, 0, stream>>>(aob, wpb, out, 1024, 1.0f, bp);
}